// Round 10
// baseline (391.903 us; speedup 1.0000x reference)
//
#include <hip/hip_runtime.h>

// ConvLSTM2D (B=16,T=5,H=W=256,Cin=3,F=8) + BN + LeakyReLU + Dense(8->2)
// Round-19: GRID-STRIDE SLOT LOOP, NO LAUNCH_BOUNDS, NO PREFETCH.
// r18 resolved the confound: long-lived blocks raise occupancy (19->30%) and
// BW (0.8->1.62 TB/s) — but launch_bounds(256,3) spilled (VGPR 84, bytes x3,
// 148us/pair). Three strikes (r13/r14/r18): min-waves spec => spill for this
// ~120-150 VGPR body. Now the isolation test: r16 pair body VERBATIM, wrapped
// in a 3-slot grid-stride loop (912 blocks x 3 tiles = 2736), natural VGPR
// (~120, 4 waves/SIMD nominal, LDS 27.1KB -> 5 blocks/CU nominal), zero extra
// registers. If occupancy rises: r18's BW at r16's bytes. If not: VALU-floor
// pivot next. lstm_last unchanged.

#define BB  16
#define TT  5
#define HH  256
#define WW  256
#define CIN 3
#define FF  8
#define GG  32

#define TW  32   // computed tile width
#define THT 16   // computed tile height
#define LW  34   // TW+2 halo
#define LH  18   // THT+2 halo
#define NG  8    // 16x16-px groups per wave

#define SW  30   // pair interior stride x
#define SH  14   // pair interior stride y
#define NPX 9    // ceil(256/30)
#define NPY 19   // ceil(256/14)
#define NTILE (NPX * NPY * BB)   // 2736
#define NBLKP 912                // 3 tiles per block, exact

#define LOG2E 1.44269504088896340736f

typedef _Float16 half8  __attribute__((ext_vector_type(8)));
typedef _Float16 half4  __attribute__((ext_vector_type(4)));
typedef _Float16 half2t __attribute__((ext_vector_type(2)));
typedef float    floatx4 __attribute__((ext_vector_type(4)));

__device__ __forceinline__ float frcp(float x) { return __builtin_amdgcn_rcpf(x); }
__device__ __forceinline__ float sig2(float z)  { return frcp(1.0f + __builtin_amdgcn_exp2f(z)); }
__device__ __forceinline__ float tanh2(float z) { return 1.0f - 2.0f * frcp(1.0f + __builtin_amdgcn_exp2f(z)); }

__device__ __forceinline__ int clampi(int v, int lo, int hi) {
    return v < lo ? lo : (v > hi ? hi : v);
}

#define MFMA(A, B, C) __builtin_amdgcn_mfma_f32_16x16x32_f16((A), (B), (C), 0, 0, 0)

#define GATES(ACC0, ACC1, C0, C1, CN0, CN1, HN0, HN1)                         \
  float CN0, CN1, HN0, HN1;                                                   \
  {                                                                           \
    float s0 = lo8 ? ACC0[2] : ACC0[0]; float r0 = __shfl_xor(s0, 8, 64);     \
    float s1 = lo8 ? ACC0[3] : ACC0[1]; float r1 = __shfl_xor(s1, 8, 64);     \
    float s2 = lo8 ? ACC1[2] : ACC1[0]; float r2 = __shfl_xor(s2, 8, 64);     \
    float s3 = lo8 ? ACC1[3] : ACC1[1]; float r3 = __shfl_xor(s3, 8, 64);     \
    const float zi0 = lo8 ? ACC0[0] : r0, zi1 = lo8 ? ACC0[1] : r1;           \
    const float zf0 = lo8 ? r0 : ACC0[2], zf1 = lo8 ? r1 : ACC0[3];           \
    const float zg0 = lo8 ? ACC1[0] : r2, zg1 = lo8 ? ACC1[1] : r3;           \
    const float zo0 = lo8 ? r2 : ACC1[2], zo1 = lo8 ? r3 : ACC1[3];           \
    const float ii0 = sig2(zi0), ff0 = sig2(zf0), gg0 = tanh2(zg0), oo0 = sig2(zo0); \
    CN0 = ff0 * (C0) + ii0 * gg0;                                             \
    HN0 = oo0 * tanh2(CN0 * (2.0f * LOG2E));                                  \
    const float ii1 = sig2(zi1), ff1 = sig2(zf1), gg1 = tanh2(zg1), oo1 = sig2(zo1); \
    CN1 = ff1 * (C1) + ii1 * gg1;                                             \
    HN1 = oo1 * tanh2(CN1 * (2.0f * LOG2E));                                  \
  }

// ---------------------------------------------------------------------------
// Setup: 16 B-fragments (unchanged; see r16 notes).
// ---------------------------------------------------------------------------
__global__ void build_frags(const float* __restrict__ wk,
                            const float* __restrict__ wr,
                            _Float16* __restrict__ blob) {
    const int lane = threadIdx.x & 63;
    const int quad = lane >> 4, nlo = lane & 15;
    for (int chunk = 0; chunk < 5; ++chunk) {
        for (int nh = 0; nh < 2; ++nh) {
            const int n = nh * 16 + nlo;
            const float scale = (n >= 16 && n < 24) ? (2.0f * LOG2E) : (-LOG2E);
            const int frag = chunk * 2 + nh;
            _Float16* dhi = blob + ((size_t)frag * 64 + lane) * 8;
            _Float16* dlo = (chunk >= 2)
                ? blob + ((size_t)(10 + (chunk - 2) * 2 + nh) * 64 + lane) * 8
                : nullptr;
            for (int j = 0; j < 8; ++j) {
                const int k = quad * 8 + j;
                float w = 0.0f;
                if (chunk == 0) {
                    int tap = k >> 2, ci = k & 3;
                    if (ci < 3) w = wk[(tap * 3 + ci) * GG + n];
                } else if (chunk == 1) {
                    if (quad == 0 && j < 3) w = wk[(8 * 3 + j) * GG + n];
                } else {
                    int c = chunk - 2;
                    int tap = c * 4 + quad, ci = j;
                    if (tap < 9) w = wr[(tap * FF + ci) * GG + n];
                }
                w *= scale;
                _Float16 wh = (_Float16)w;
                dhi[j] = wh;
                if (dlo) dlo[j] = (_Float16)(w - (float)wh);
            }
        }
    }
}

// ---------------------------------------------------------------------------
// Pair kernel: 912 blocks, each processes 3 tiles (grid-stride). Per tile:
// steps t (full 32x16) and t+1 (interior 30x14 written). Body = r16 verbatim.
// ---------------------------------------------------------------------------
template <int FIRSTPAIR>
__global__ void lstm_pair(
    const float* __restrict__ xg,       // [B,T,H,W,3] fp32
    int t,
    const _Float16* __restrict__ blob,
    const float* __restrict__ bias,
    const _Float16* __restrict__ hin,   // h(t-1) plain [b,y,x,8]
    _Float16* __restrict__ hout,        // h(t+1) plain
    const _Float16* __restrict__ cin,   // c(t-1) plain
    _Float16* __restrict__ cout)        // c(t+1) plain
{
    __shared__ half8 hls1[LH * LW];                        // h(t-1) halo (9792 B)
    __shared__ half4 xls1[LH * LW];                        // x(t) halo   (4896 B)
    __shared__ half4 xls2[THT * TW];                       // x(t+1) tile (4096 B)
    __shared__ __align__(16) _Float16 hls2[THT * TW * FF]; // h(t) tile   (8192 B)

    const int tid  = threadIdx.x;
    const int lane = tid & 63, wave = tid >> 6;
    const int quad = lane >> 4, nlo = lane & 15;
    const bool lo8 = (nlo < 8);
    const int fc = nlo & 7;
    const int m0 = quad * 4 + (lo8 ? 0 : 2);

    // B-fragments once (L2-hot)
    half8 bfh[10], bfl[6];
#pragma unroll
    for (int i = 0; i < 10; ++i)
        bfh[i] = *(const half8*)(blob + ((size_t)i * 64 + lane) * 8);
#pragma unroll
    for (int i = 0; i < 6; ++i)
        bfl[i] = *(const half8*)(blob + ((size_t)(10 + i) * 64 + lane) * 8);

    const float bv0 = bias[nlo] * (-LOG2E);
    const float bv1 = bias[16 + nlo] * (lo8 ? 2.0f * LOG2E : -LOG2E);

#pragma unroll 1
    for (int tile = (int)blockIdx.x; tile < NTILE; tile += NBLKP) {
        const int b  = tile / (NPX * NPY);
        const int rm = tile - b * (NPX * NPY);
        const int by = rm / NPX;
        const int bx = rm - by * NPX;
        const int x0 = bx * SW - 1, y0 = by * SH - 1;   // computed-tile origin

        // ============ PHASE A: issue ALL global loads ============
        float xr1[3][3];
        bool  xin1[3];
#pragma unroll
        for (int k = 0; k < 3; ++k) {
            const int l = tid + k * 256;
            const bool in = (l < LH * LW);
            xin1[k] = in;
            int r = l / LW, c = l - r * LW;
            int gy = y0 - 1 + r, gx = x0 - 1 + c;
            const bool inb = in && (unsigned)gy < HH && (unsigned)gx < WW;
            const float* p = xg + (((size_t)(b * TT + t) * HH + gy) * WW + gx) * CIN;
            xr1[k][0] = inb ? p[0] : 0.0f;
            xr1[k][1] = inb ? p[1] : 0.0f;
            xr1[k][2] = inb ? p[2] : 0.0f;
        }
        float xr2[2][3];
#pragma unroll
        for (int k = 0; k < 2; ++k) {
            const int l = tid + k * 256;
            int r = l >> 5, c = l & 31;
            int gy = y0 + r, gx = x0 + c;
            const bool inb = (unsigned)gy < HH && (unsigned)gx < WW;
            const float* p = xg + (((size_t)(b * TT + t + 1) * HH + gy) * WW + gx) * CIN;
            xr2[k][0] = inb ? p[0] : 0.0f;
            xr2[k][1] = inb ? p[1] : 0.0f;
            xr2[k][2] = inb ? p[2] : 0.0f;
        }
        half8 hr[3];
        if (!FIRSTPAIR) {
#pragma unroll
            for (int k = 0; k < 3; ++k) {
                const int l = tid + k * 256;
                const bool in = (l < LH * LW);
                int r = l / LW, c = l - r * LW;
                int gy = y0 - 1 + r, gx = x0 - 1 + c;
                const bool inb = in && (unsigned)gy < HH && (unsigned)gx < WW;
                half8 v = {(_Float16)0, (_Float16)0, (_Float16)0, (_Float16)0,
                           (_Float16)0, (_Float16)0, (_Float16)0, (_Float16)0};
                if (inb) v = *(const half8*)(hin + ((size_t)(b * HH + gy) * WW + gx) * FF);
                hr[k] = v;
            }
        }
        half2t cpre[NG];
        if (!FIRSTPAIR) {
#pragma unroll
            for (int g = 0; g < NG; ++g) {
                const int lr  = wave * 4 + (g >> 1);
                const int gx0 = (g & 1) * 16;
                const int gy  = y0 + lr;
                const int gxa = x0 + gx0 + m0;
                const bool iny = (unsigned)gy < HH;
                half2t cv; cv.x = (_Float16)0; cv.y = (_Float16)0;
                const _Float16* cp = cin + ((size_t)(b * HH + gy) * WW + gxa) * FF + fc;
                if (iny && (unsigned)gxa < WW)       cv.x = cp[0];
                if (iny && (unsigned)(gxa + 1) < WW) cv.y = cp[FF];
                cpre[g] = cv;
            }
        }

        // LDS safe to overwrite only after prev tile's readers are done
        __syncthreads();

        // ============ PHASE B: LDS writes ============
#pragma unroll
        for (int k = 0; k < 3; ++k) {
            if (xin1[k]) {
                half4 vh;
                vh.x = (_Float16)xr1[k][0];
                vh.y = (_Float16)xr1[k][1];
                vh.z = (_Float16)xr1[k][2];
                vh.w = (_Float16)0;
                xls1[tid + k * 256] = vh;
            }
        }
#pragma unroll
        for (int k = 0; k < 2; ++k) {
            half4 vh;
            vh.x = (_Float16)xr2[k][0];
            vh.y = (_Float16)xr2[k][1];
            vh.z = (_Float16)xr2[k][2];
            vh.w = (_Float16)0;
            xls2[tid + k * 256] = vh;
        }
        if (!FIRSTPAIR) {
#pragma unroll
            for (int k = 0; k < 3; ++k)
                if (xin1[k]) hls1[tid + k * 256] = hr[k];
        }
        __syncthreads();

        // ============ PHASE C: step t on full 32x16 ============
        half2t creg[NG];
#pragma unroll
        for (int g = 0; g < NG; ++g) {
            const int lr  = wave * 4 + (g >> 1);
            const int gx0 = (g & 1) * 16;
            const int lc  = gx0 + nlo;

            const int t0 = 2 * quad, t1 = t0 + 1;
            half4 p  = xls1[(lr + t0 / 3) * LW + lc + t0 % 3];
            half4 q  = xls1[(lr + t1 / 3) * LW + lc + t1 % 3];
            half4 s8 = xls1[(lr + 2) * LW + lc + 2];            // tap 8
            half8 a_xA = (half8){p.x, p.y, p.z, p.w, q.x, q.y, q.z, q.w};
            half8 a_xB = (half8){s8.x, s8.y, s8.z, s8.w, s8.x, s8.y, s8.z, s8.w};

            floatx4 acc0 = {bv0, bv0, bv0, bv0};
            floatx4 acc1 = {bv1, bv1, bv1, bv1};
            acc0 = MFMA(a_xA, bfh[0], acc0);  acc1 = MFMA(a_xA, bfh[1], acc1);
            acc0 = MFMA(a_xB, bfh[2], acc0);  acc1 = MFMA(a_xB, bfh[3], acc1);
            if (!FIRSTPAIR) {
#pragma unroll
                for (int c = 0; c < 3; ++c) {
                    int tap = c * 4 + quad;
                    if (tap > 8) tap = 8;          // padded taps: B rows zero
                    half8 ah = hls1[(lr + tap / 3) * LW + lc + tap % 3];
                    acc0 = MFMA(ah, bfh[4 + c * 2], acc0);
                    acc1 = MFMA(ah, bfh[5 + c * 2], acc1);
                    acc0 = MFMA(ah, bfl[c * 2 + 0], acc0);
                    acc1 = MFMA(ah, bfl[c * 2 + 1], acc1);
                }
            }

            GATES(acc0, acc1,
                  FIRSTPAIR ? 0.0f : (float)cpre[g].x,
                  FIRSTPAIR ? 0.0f : (float)cpre[g].y,
                  cn0, cn1, hn0, hn1);

            half2t cc; cc.x = (_Float16)cn0; cc.y = (_Float16)cn1;
            creg[g] = cc;

            // h(t) -> LDS, zero-masked outside the image ('SAME' padding)
            const int gy   = y0 + lr;
            const int colm = gx0 + m0;
            const int gxa  = x0 + colm;
            const bool iny = (unsigned)gy < HH;
            _Float16 h0v = (_Float16)hn0, h1v = (_Float16)hn1;
            if (!(iny && (unsigned)gxa < WW))       h0v = (_Float16)0;
            if (!(iny && (unsigned)(gxa + 1) < WW)) h1v = (_Float16)0;
            hls2[(lr * TW + colm) * FF + fc]     = h0v;
            hls2[(lr * TW + colm + 1) * FF + fc] = h1v;
        }
        __syncthreads();

        // ============ PHASE D: step t+1, interior 30x14 ============
#pragma unroll
        for (int g = 0; g < NG; ++g) {
            const int lr  = wave * 4 + (g >> 1);
            const int gx0 = (g & 1) * 16;
            const int lc  = gx0 + nlo;

            const int t0 = 2 * quad, t1 = t0 + 1;
            half4 p  = xls2[clampi(lr + t0 / 3 - 1, 0, THT - 1) * TW + clampi(lc + t0 % 3 - 1, 0, TW - 1)];
            half4 q  = xls2[clampi(lr + t1 / 3 - 1, 0, THT - 1) * TW + clampi(lc + t1 % 3 - 1, 0, TW - 1)];
            half4 s8 = xls2[clampi(lr + 1, 0, THT - 1) * TW + clampi(lc + 1, 0, TW - 1)];
            half8 a_xA = (half8){p.x, p.y, p.z, p.w, q.x, q.y, q.z, q.w};
            half8 a_xB = (half8){s8.x, s8.y, s8.z, s8.w, s8.x, s8.y, s8.z, s8.w};

            floatx4 acc0 = {bv0, bv0, bv0, bv0};
            floatx4 acc1 = {bv1, bv1, bv1, bv1};
            acc0 = MFMA(a_xA, bfh[0], acc0);  acc1 = MFMA(a_xA, bfh[1], acc1);
            acc0 = MFMA(a_xB, bfh[2], acc0);  acc1 = MFMA(a_xB, bfh[3], acc1);
#pragma unroll
            for (int c = 0; c < 3; ++c) {
                int tap = c * 4 + quad;
                if (tap > 8) tap = 8;
                const int rr = clampi(lr + tap / 3 - 1, 0, THT - 1);
                const int cc = clampi(lc + tap % 3 - 1, 0, TW - 1);
                half8 ah = *(const half8*)(hls2 + (rr * TW + cc) * FF);
                acc0 = MFMA(ah, bfh[4 + c * 2], acc0);
                acc1 = MFMA(ah, bfh[5 + c * 2], acc1);
                acc0 = MFMA(ah, bfl[c * 2 + 0], acc0);
                acc1 = MFMA(ah, bfl[c * 2 + 1], acc1);
            }

            GATES(acc0, acc1, (float)creg[g].x, (float)creg[g].y, cn0, cn1, hn0, hn1);

            const int gy   = y0 + lr;
            const int colm = gx0 + m0;
            const int gxa  = x0 + colm;
            const bool rowok = (lr >= 1) && (lr <= SH) && ((unsigned)gy < HH);
            const bool c0ok = rowok && (colm >= 1) && (colm <= SW) && ((unsigned)gxa < WW);
            const bool c1ok = rowok && (colm + 1 <= SW) && ((unsigned)(gxa + 1) < WW);
            const size_t base = ((size_t)(b * HH + gy) * WW + gxa) * FF + fc;
            if (c0ok) {
                hout[base] = (_Float16)hn0;
                cout[base] = (_Float16)cn0;
            }
            if (c1ok) {
                hout[base + FF] = (_Float16)hn1;
                cout[base + FF] = (_Float16)cn1;
            }
        }
    }
}

// ---------------------------------------------------------------------------
// Last step (t=4) + fused epilogue. Non-overlapping 32x16 tiles (r16 verbatim).
// ---------------------------------------------------------------------------
__global__ __launch_bounds__(256) void lstm_last(
    const float* __restrict__ xg,
    const _Float16* __restrict__ blob,
    const float* __restrict__ bias,
    const _Float16* __restrict__ hin,   // h(3)
    const _Float16* __restrict__ cin,   // c(3) plain
    const float* __restrict__ gamma, const float* __restrict__ beta,
    const float* __restrict__ mean,  const float* __restrict__ var,
    const float* __restrict__ dw,    const float* __restrict__ db,
    float* __restrict__ out)            // [B,H,W,2]
{
    __shared__ half8 hls[LH * LW];
    __shared__ half4 xls[LH * LW];

    const int tid  = threadIdx.x;
    const int lane = tid & 63, wave = tid >> 6;
    const int quad = lane >> 4, nlo = lane & 15;
    const bool lo8 = (nlo < 8);
    const int fc = nlo & 7;
    const int m0 = quad * 4 + (lo8 ? 0 : 2);
    const int bx = blockIdx.x, by = blockIdx.y, b = blockIdx.z;
    const int t = TT - 1;

    half8 bfh[10], bfl[6];
#pragma unroll
    for (int i = 0; i < 10; ++i)
        bfh[i] = *(const half8*)(blob + ((size_t)i * 64 + lane) * 8);
#pragma unroll
    for (int i = 0; i < 6; ++i)
        bfl[i] = *(const half8*)(blob + ((size_t)(10 + i) * 64 + lane) * 8);

    const float bv0 = bias[nlo] * (-LOG2E);
    const float bv1 = bias[16 + nlo] * (lo8 ? 2.0f * LOG2E : -LOG2E);

    float xr[3][3];
    bool  xin[3];
#pragma unroll
    for (int k = 0; k < 3; ++k) {
        const int l = tid + k * 256;
        const bool in = (l < LH * LW);
        xin[k] = in;
        int r = l / LW, c = l - r * LW;
        int gy = by * THT + r - 1, gx = bx * TW + c - 1;
        const bool inb = in && (unsigned)gy < HH && (unsigned)gx < WW;
        const float* p = xg + (((size_t)(b * TT + t) * HH + gy) * WW + gx) * CIN;
        xr[k][0] = inb ? p[0] : 0.0f;
        xr[k][1] = inb ? p[1] : 0.0f;
        xr[k][2] = inb ? p[2] : 0.0f;
    }
    half8 hr[3];
#pragma unroll
    for (int k = 0; k < 3; ++k) {
        const int l = tid + k * 256;
        const bool in = (l < LH * LW);
        int r = l / LW, c = l - r * LW;
        int gy = by * THT + r - 1, gx = bx * TW + c - 1;
        const bool inb = in && (unsigned)gy < HH && (unsigned)gx < WW;
        half8 v = {(_Float16)0, (_Float16)0, (_Float16)0, (_Float16)0,
                   (_Float16)0, (_Float16)0, (_Float16)0, (_Float16)0};
        if (inb) v = *(const half8*)(hin + ((size_t)(b * HH + gy) * WW + gx) * FF);
        hr[k] = v;
    }
    half2t cpre[NG];
#pragma unroll
    for (int g = 0; g < NG; ++g) {
        const int lr  = wave * 4 + (g >> 1);
        const int gx0 = (g & 1) * 16;
        const int gy  = by * THT + lr;
        const int gxa = bx * TW + gx0 + m0;
        const _Float16* cp = cin + ((size_t)(b * HH + gy) * WW + gxa) * FF + fc;
        half2t cv; cv.x = cp[0]; cv.y = cp[FF];
        cpre[g] = cv;
    }

#pragma unroll
    for (int k = 0; k < 3; ++k) {
        if (xin[k]) {
            half4 vh;
            vh.x = (_Float16)xr[k][0];
            vh.y = (_Float16)xr[k][1];
            vh.z = (_Float16)xr[k][2];
            vh.w = (_Float16)0;
            xls[tid + k * 256] = vh;
            hls[tid + k * 256] = hr[k];
        }
    }
    __syncthreads();

    const float bn_s = gamma[fc] * rsqrtf(var[fc] + 1e-3f);
    const float bn_b = beta[fc] - mean[fc] * bn_s;
    const float dw0 = dw[fc * 2 + 0], dw1 = dw[fc * 2 + 1];
    const float db0 = db[0], db1 = db[1];

#pragma unroll
    for (int g = 0; g < NG; ++g) {
        const int lr  = wave * 4 + (g >> 1);
        const int gx0 = (g & 1) * 16;
        const int lc  = gx0 + nlo;

        const int t0 = 2 * quad, t1 = t0 + 1;
        half4 p  = xls[(lr + t0 / 3) * LW + lc + t0 % 3];
        half4 q  = xls[(lr + t1 / 3) * LW + lc + t1 % 3];
        half4 s8 = xls[(lr + 2) * LW + lc + 2];
        half8 a_xA = (half8){p.x, p.y, p.z, p.w, q.x, q.y, q.z, q.w};
        half8 a_xB = (half8){s8.x, s8.y, s8.z, s8.w, s8.x, s8.y, s8.z, s8.w};

        floatx4 acc0 = {bv0, bv0, bv0, bv0};
        floatx4 acc1 = {bv1, bv1, bv1, bv1};
        acc0 = MFMA(a_xA, bfh[0], acc0);  acc1 = MFMA(a_xA, bfh[1], acc1);
        acc0 = MFMA(a_xB, bfh[2], acc0);  acc1 = MFMA(a_xB, bfh[3], acc1);
#pragma unroll
        for (int c = 0; c < 3; ++c) {
            int tap = c * 4 + quad;
            if (tap > 8) tap = 8;
            half8 ah = hls[(lr + tap / 3) * LW + lc + tap % 3];
            acc0 = MFMA(ah, bfh[4 + c * 2], acc0);
            acc1 = MFMA(ah, bfh[5 + c * 2], acc1);
            acc0 = MFMA(ah, bfl[c * 2 + 0], acc0);
            acc1 = MFMA(ah, bfl[c * 2 + 1], acc1);
        }

        GATES(acc0, acc1, (float)cpre[g].x, (float)cpre[g].y, cn0, cn1, hn0, hn1);
        (void)cn0; (void)cn1;

        const int gy = by * THT + lr;
        float y0 = bn_s * hn0 + bn_b; y0 = (y0 >= 0.f) ? y0 : 0.3f * y0;
        float y1 = bn_s * hn1 + bn_b; y1 = (y1 >= 0.f) ? y1 : 0.3f * y1;
        float p00 = y0 * dw0, p01 = y0 * dw1;
        float p10 = y1 * dw0, p11 = y1 * dw1;
#pragma unroll
        for (int m = 1; m <= 4; m <<= 1) {
            p00 += __shfl_xor(p00, m, 64);
            p01 += __shfl_xor(p01, m, 64);
            p10 += __shfl_xor(p10, m, 64);
            p11 += __shfl_xor(p11, m, 64);
        }
        const int j = nlo & 7;
        if (j < 4) {
            const int px = m0 + (j >> 1);
            const int k  = j & 1;
            float val = (j == 0 ? p00 : j == 1 ? p01 : j == 2 ? p10 : p11)
                        + (k ? db1 : db0);
            out[((size_t)(b * HH + gy) * WW + bx * TW + gx0 + px) * 2 + k] = val;
        }
    }
}

extern "C" void kernel_launch(void* const* d_in, const int* in_sizes, int n_in,
                              void* d_out, int out_size, void* d_ws, size_t ws_size,
                              hipStream_t stream) {
    const float* x     = (const float*)d_in[0];
    const float* wk    = (const float*)d_in[1];
    const float* wr    = (const float*)d_in[2];
    const float* bias  = (const float*)d_in[3];
    const float* gamma = (const float*)d_in[4];
    const float* beta  = (const float*)d_in[5];
    const float* mean  = (const float*)d_in[6];
    const float* var   = (const float*)d_in[7];
    const float* dw    = (const float*)d_in[8];
    const float* db    = (const float*)d_in[9];
    float* out = (float*)d_out;

    // ws: blob 32KB | hA | hB | cA | cB (each 16.78MB fp16) = 67.2MB total
    const size_t state = (size_t)BB * HH * WW * FF;
    _Float16* blob = (_Float16*)d_ws;
    _Float16* hA = (_Float16*)((char*)d_ws + 32768);
    _Float16* hB = hA + state;
    _Float16* cA = hB + state;
    _Float16* cB = cA + state;

    build_frags<<<1, 64, 0, stream>>>(wk, wr, blob);

    dim3 block(256);
    // pair (0,1): no h/c input; writes h(1)->hA, c(1)->cA
    lstm_pair<1><<<dim3(NBLKP), block, 0, stream>>>(x, 0, blob, bias,
                                                    nullptr, hA, nullptr, cA);
    // pair (2,3): reads hA/cA; writes h(3)->hB, c(3)->cB
    lstm_pair<0><<<dim3(NBLKP), block, 0, stream>>>(x, 2, blob, bias,
                                                    hA, hB, cA, cB);
    // step 4 + epilogue
    dim3 lgrid(WW / TW, HH / THT, BB);
    lstm_last<<<lgrid, block, 0, stream>>>(x, blob, bias, hB, cB,
                                           gamma, beta, mean, var, dw, db, out);
}

// Round 11
// 298.449 us; speedup vs baseline: 1.3131x; 1.3131x over previous
//
#include <hip/hip_runtime.h>

// ConvLSTM2D (B=16,T=5,H=W=256,Cin=3,F=8) + BN + LeakyReLU + Dense(8->2)
// Round-20: r19 + __launch_bounds__(256) on lstm_pair. ONE-TOKEN DELTA.
// r19's spill (VGPR 64!) came from hipcc's DEFAULT 1024-thread launch-bounds
// assumption — no launch_bounds is itself a tight cap. Ledger:
//   launch_bounds(256)   -> VGPR 120, no spill (r16/r17)
//   launch_bounds(256,2+) -> 84-128, spill (r13/r18)
//   none                  -> 64, spill (r19)
// r19 proved grid-stride long-lived blocks sustain 2.08 TB/s / 37% occ even
// WHILE spilling. This round: same structure, natural 120-VGPR allocation.
// Expect r16 bytes (45+33 MB) at r18/r19 bandwidth.

#define BB  16
#define TT  5
#define HH  256
#define WW  256
#define CIN 3
#define FF  8
#define GG  32

#define TW  32   // computed tile width
#define THT 16   // computed tile height
#define LW  34   // TW+2 halo
#define LH  18   // THT+2 halo
#define NG  8    // 16x16-px groups per wave

#define SW  30   // pair interior stride x
#define SH  14   // pair interior stride y
#define NPX 9    // ceil(256/30)
#define NPY 19   // ceil(256/14)
#define NTILE (NPX * NPY * BB)   // 2736
#define NBLKP 912                // 3 tiles per block, exact

#define LOG2E 1.44269504088896340736f

typedef _Float16 half8  __attribute__((ext_vector_type(8)));
typedef _Float16 half4  __attribute__((ext_vector_type(4)));
typedef _Float16 half2t __attribute__((ext_vector_type(2)));
typedef float    floatx4 __attribute__((ext_vector_type(4)));

__device__ __forceinline__ float frcp(float x) { return __builtin_amdgcn_rcpf(x); }
__device__ __forceinline__ float sig2(float z)  { return frcp(1.0f + __builtin_amdgcn_exp2f(z)); }
__device__ __forceinline__ float tanh2(float z) { return 1.0f - 2.0f * frcp(1.0f + __builtin_amdgcn_exp2f(z)); }

__device__ __forceinline__ int clampi(int v, int lo, int hi) {
    return v < lo ? lo : (v > hi ? hi : v);
}

#define MFMA(A, B, C) __builtin_amdgcn_mfma_f32_16x16x32_f16((A), (B), (C), 0, 0, 0)

#define GATES(ACC0, ACC1, C0, C1, CN0, CN1, HN0, HN1)                         \
  float CN0, CN1, HN0, HN1;                                                   \
  {                                                                           \
    float s0 = lo8 ? ACC0[2] : ACC0[0]; float r0 = __shfl_xor(s0, 8, 64);     \
    float s1 = lo8 ? ACC0[3] : ACC0[1]; float r1 = __shfl_xor(s1, 8, 64);     \
    float s2 = lo8 ? ACC1[2] : ACC1[0]; float r2 = __shfl_xor(s2, 8, 64);     \
    float s3 = lo8 ? ACC1[3] : ACC1[1]; float r3 = __shfl_xor(s3, 8, 64);     \
    const float zi0 = lo8 ? ACC0[0] : r0, zi1 = lo8 ? ACC0[1] : r1;           \
    const float zf0 = lo8 ? r0 : ACC0[2], zf1 = lo8 ? r1 : ACC0[3];           \
    const float zg0 = lo8 ? ACC1[0] : r2, zg1 = lo8 ? ACC1[1] : r3;           \
    const float zo0 = lo8 ? r2 : ACC1[2], zo1 = lo8 ? r3 : ACC1[3];           \
    const float ii0 = sig2(zi0), ff0 = sig2(zf0), gg0 = tanh2(zg0), oo0 = sig2(zo0); \
    CN0 = ff0 * (C0) + ii0 * gg0;                                             \
    HN0 = oo0 * tanh2(CN0 * (2.0f * LOG2E));                                  \
    const float ii1 = sig2(zi1), ff1 = sig2(zf1), gg1 = tanh2(zg1), oo1 = sig2(zo1); \
    CN1 = ff1 * (C1) + ii1 * gg1;                                             \
    HN1 = oo1 * tanh2(CN1 * (2.0f * LOG2E));                                  \
  }

// ---------------------------------------------------------------------------
// Setup: 16 B-fragments (unchanged; see r16 notes).
// ---------------------------------------------------------------------------
__global__ void build_frags(const float* __restrict__ wk,
                            const float* __restrict__ wr,
                            _Float16* __restrict__ blob) {
    const int lane = threadIdx.x & 63;
    const int quad = lane >> 4, nlo = lane & 15;
    for (int chunk = 0; chunk < 5; ++chunk) {
        for (int nh = 0; nh < 2; ++nh) {
            const int n = nh * 16 + nlo;
            const float scale = (n >= 16 && n < 24) ? (2.0f * LOG2E) : (-LOG2E);
            const int frag = chunk * 2 + nh;
            _Float16* dhi = blob + ((size_t)frag * 64 + lane) * 8;
            _Float16* dlo = (chunk >= 2)
                ? blob + ((size_t)(10 + (chunk - 2) * 2 + nh) * 64 + lane) * 8
                : nullptr;
            for (int j = 0; j < 8; ++j) {
                const int k = quad * 8 + j;
                float w = 0.0f;
                if (chunk == 0) {
                    int tap = k >> 2, ci = k & 3;
                    if (ci < 3) w = wk[(tap * 3 + ci) * GG + n];
                } else if (chunk == 1) {
                    if (quad == 0 && j < 3) w = wk[(8 * 3 + j) * GG + n];
                } else {
                    int c = chunk - 2;
                    int tap = c * 4 + quad, ci = j;
                    if (tap < 9) w = wr[(tap * FF + ci) * GG + n];
                }
                w *= scale;
                _Float16 wh = (_Float16)w;
                dhi[j] = wh;
                if (dlo) dlo[j] = (_Float16)(w - (float)wh);
            }
        }
    }
}

// ---------------------------------------------------------------------------
// Pair kernel: 912 blocks, each processes 3 tiles (grid-stride). Per tile:
// steps t (full 32x16) and t+1 (interior 30x14 written). Body = r16 verbatim.
// ---------------------------------------------------------------------------
template <int FIRSTPAIR>
__global__ __launch_bounds__(256) void lstm_pair(
    const float* __restrict__ xg,       // [B,T,H,W,3] fp32
    int t,
    const _Float16* __restrict__ blob,
    const float* __restrict__ bias,
    const _Float16* __restrict__ hin,   // h(t-1) plain [b,y,x,8]
    _Float16* __restrict__ hout,        // h(t+1) plain
    const _Float16* __restrict__ cin,   // c(t-1) plain
    _Float16* __restrict__ cout)        // c(t+1) plain
{
    __shared__ half8 hls1[LH * LW];                        // h(t-1) halo (9792 B)
    __shared__ half4 xls1[LH * LW];                        // x(t) halo   (4896 B)
    __shared__ half4 xls2[THT * TW];                       // x(t+1) tile (4096 B)
    __shared__ __align__(16) _Float16 hls2[THT * TW * FF]; // h(t) tile   (8192 B)

    const int tid  = threadIdx.x;
    const int lane = tid & 63, wave = tid >> 6;
    const int quad = lane >> 4, nlo = lane & 15;
    const bool lo8 = (nlo < 8);
    const int fc = nlo & 7;
    const int m0 = quad * 4 + (lo8 ? 0 : 2);

    // B-fragments once (L2-hot)
    half8 bfh[10], bfl[6];
#pragma unroll
    for (int i = 0; i < 10; ++i)
        bfh[i] = *(const half8*)(blob + ((size_t)i * 64 + lane) * 8);
#pragma unroll
    for (int i = 0; i < 6; ++i)
        bfl[i] = *(const half8*)(blob + ((size_t)(10 + i) * 64 + lane) * 8);

    const float bv0 = bias[nlo] * (-LOG2E);
    const float bv1 = bias[16 + nlo] * (lo8 ? 2.0f * LOG2E : -LOG2E);

#pragma unroll 1
    for (int tile = (int)blockIdx.x; tile < NTILE; tile += NBLKP) {
        const int b  = tile / (NPX * NPY);
        const int rm = tile - b * (NPX * NPY);
        const int by = rm / NPX;
        const int bx = rm - by * NPX;
        const int x0 = bx * SW - 1, y0 = by * SH - 1;   // computed-tile origin

        // ============ PHASE A: issue ALL global loads ============
        float xr1[3][3];
        bool  xin1[3];
#pragma unroll
        for (int k = 0; k < 3; ++k) {
            const int l = tid + k * 256;
            const bool in = (l < LH * LW);
            xin1[k] = in;
            int r = l / LW, c = l - r * LW;
            int gy = y0 - 1 + r, gx = x0 - 1 + c;
            const bool inb = in && (unsigned)gy < HH && (unsigned)gx < WW;
            const float* p = xg + (((size_t)(b * TT + t) * HH + gy) * WW + gx) * CIN;
            xr1[k][0] = inb ? p[0] : 0.0f;
            xr1[k][1] = inb ? p[1] : 0.0f;
            xr1[k][2] = inb ? p[2] : 0.0f;
        }
        float xr2[2][3];
#pragma unroll
        for (int k = 0; k < 2; ++k) {
            const int l = tid + k * 256;
            int r = l >> 5, c = l & 31;
            int gy = y0 + r, gx = x0 + c;
            const bool inb = (unsigned)gy < HH && (unsigned)gx < WW;
            const float* p = xg + (((size_t)(b * TT + t + 1) * HH + gy) * WW + gx) * CIN;
            xr2[k][0] = inb ? p[0] : 0.0f;
            xr2[k][1] = inb ? p[1] : 0.0f;
            xr2[k][2] = inb ? p[2] : 0.0f;
        }
        half8 hr[3];
        if (!FIRSTPAIR) {
#pragma unroll
            for (int k = 0; k < 3; ++k) {
                const int l = tid + k * 256;
                const bool in = (l < LH * LW);
                int r = l / LW, c = l - r * LW;
                int gy = y0 - 1 + r, gx = x0 - 1 + c;
                const bool inb = in && (unsigned)gy < HH && (unsigned)gx < WW;
                half8 v = {(_Float16)0, (_Float16)0, (_Float16)0, (_Float16)0,
                           (_Float16)0, (_Float16)0, (_Float16)0, (_Float16)0};
                if (inb) v = *(const half8*)(hin + ((size_t)(b * HH + gy) * WW + gx) * FF);
                hr[k] = v;
            }
        }
        half2t cpre[NG];
        if (!FIRSTPAIR) {
#pragma unroll
            for (int g = 0; g < NG; ++g) {
                const int lr  = wave * 4 + (g >> 1);
                const int gx0 = (g & 1) * 16;
                const int gy  = y0 + lr;
                const int gxa = x0 + gx0 + m0;
                const bool iny = (unsigned)gy < HH;
                half2t cv; cv.x = (_Float16)0; cv.y = (_Float16)0;
                const _Float16* cp = cin + ((size_t)(b * HH + gy) * WW + gxa) * FF + fc;
                if (iny && (unsigned)gxa < WW)       cv.x = cp[0];
                if (iny && (unsigned)(gxa + 1) < WW) cv.y = cp[FF];
                cpre[g] = cv;
            }
        }

        // LDS safe to overwrite only after prev tile's readers are done
        __syncthreads();

        // ============ PHASE B: LDS writes ============
#pragma unroll
        for (int k = 0; k < 3; ++k) {
            if (xin1[k]) {
                half4 vh;
                vh.x = (_Float16)xr1[k][0];
                vh.y = (_Float16)xr1[k][1];
                vh.z = (_Float16)xr1[k][2];
                vh.w = (_Float16)0;
                xls1[tid + k * 256] = vh;
            }
        }
#pragma unroll
        for (int k = 0; k < 2; ++k) {
            half4 vh;
            vh.x = (_Float16)xr2[k][0];
            vh.y = (_Float16)xr2[k][1];
            vh.z = (_Float16)xr2[k][2];
            vh.w = (_Float16)0;
            xls2[tid + k * 256] = vh;
        }
        if (!FIRSTPAIR) {
#pragma unroll
            for (int k = 0; k < 3; ++k)
                if (xin1[k]) hls1[tid + k * 256] = hr[k];
        }
        __syncthreads();

        // ============ PHASE C: step t on full 32x16 ============
        half2t creg[NG];
#pragma unroll
        for (int g = 0; g < NG; ++g) {
            const int lr  = wave * 4 + (g >> 1);
            const int gx0 = (g & 1) * 16;
            const int lc  = gx0 + nlo;

            const int t0 = 2 * quad, t1 = t0 + 1;
            half4 p  = xls1[(lr + t0 / 3) * LW + lc + t0 % 3];
            half4 q  = xls1[(lr + t1 / 3) * LW + lc + t1 % 3];
            half4 s8 = xls1[(lr + 2) * LW + lc + 2];            // tap 8
            half8 a_xA = (half8){p.x, p.y, p.z, p.w, q.x, q.y, q.z, q.w};
            half8 a_xB = (half8){s8.x, s8.y, s8.z, s8.w, s8.x, s8.y, s8.z, s8.w};

            floatx4 acc0 = {bv0, bv0, bv0, bv0};
            floatx4 acc1 = {bv1, bv1, bv1, bv1};
            acc0 = MFMA(a_xA, bfh[0], acc0);  acc1 = MFMA(a_xA, bfh[1], acc1);
            acc0 = MFMA(a_xB, bfh[2], acc0);  acc1 = MFMA(a_xB, bfh[3], acc1);
            if (!FIRSTPAIR) {
#pragma unroll
                for (int c = 0; c < 3; ++c) {
                    int tap = c * 4 + quad;
                    if (tap > 8) tap = 8;          // padded taps: B rows zero
                    half8 ah = hls1[(lr + tap / 3) * LW + lc + tap % 3];
                    acc0 = MFMA(ah, bfh[4 + c * 2], acc0);
                    acc1 = MFMA(ah, bfh[5 + c * 2], acc1);
                    acc0 = MFMA(ah, bfl[c * 2 + 0], acc0);
                    acc1 = MFMA(ah, bfl[c * 2 + 1], acc1);
                }
            }

            GATES(acc0, acc1,
                  FIRSTPAIR ? 0.0f : (float)cpre[g].x,
                  FIRSTPAIR ? 0.0f : (float)cpre[g].y,
                  cn0, cn1, hn0, hn1);

            half2t cc; cc.x = (_Float16)cn0; cc.y = (_Float16)cn1;
            creg[g] = cc;

            // h(t) -> LDS, zero-masked outside the image ('SAME' padding)
            const int gy   = y0 + lr;
            const int colm = gx0 + m0;
            const int gxa  = x0 + colm;
            const bool iny = (unsigned)gy < HH;
            _Float16 h0v = (_Float16)hn0, h1v = (_Float16)hn1;
            if (!(iny && (unsigned)gxa < WW))       h0v = (_Float16)0;
            if (!(iny && (unsigned)(gxa + 1) < WW)) h1v = (_Float16)0;
            hls2[(lr * TW + colm) * FF + fc]     = h0v;
            hls2[(lr * TW + colm + 1) * FF + fc] = h1v;
        }
        __syncthreads();

        // ============ PHASE D: step t+1, interior 30x14 ============
#pragma unroll
        for (int g = 0; g < NG; ++g) {
            const int lr  = wave * 4 + (g >> 1);
            const int gx0 = (g & 1) * 16;
            const int lc  = gx0 + nlo;

            const int t0 = 2 * quad, t1 = t0 + 1;
            half4 p  = xls2[clampi(lr + t0 / 3 - 1, 0, THT - 1) * TW + clampi(lc + t0 % 3 - 1, 0, TW - 1)];
            half4 q  = xls2[clampi(lr + t1 / 3 - 1, 0, THT - 1) * TW + clampi(lc + t1 % 3 - 1, 0, TW - 1)];
            half4 s8 = xls2[clampi(lr + 1, 0, THT - 1) * TW + clampi(lc + 1, 0, TW - 1)];
            half8 a_xA = (half8){p.x, p.y, p.z, p.w, q.x, q.y, q.z, q.w};
            half8 a_xB = (half8){s8.x, s8.y, s8.z, s8.w, s8.x, s8.y, s8.z, s8.w};

            floatx4 acc0 = {bv0, bv0, bv0, bv0};
            floatx4 acc1 = {bv1, bv1, bv1, bv1};
            acc0 = MFMA(a_xA, bfh[0], acc0);  acc1 = MFMA(a_xA, bfh[1], acc1);
            acc0 = MFMA(a_xB, bfh[2], acc0);  acc1 = MFMA(a_xB, bfh[3], acc1);
#pragma unroll
            for (int c = 0; c < 3; ++c) {
                int tap = c * 4 + quad;
                if (tap > 8) tap = 8;
                const int rr = clampi(lr + tap / 3 - 1, 0, THT - 1);
                const int cc = clampi(lc + tap % 3 - 1, 0, TW - 1);
                half8 ah = *(const half8*)(hls2 + (rr * TW + cc) * FF);
                acc0 = MFMA(ah, bfh[4 + c * 2], acc0);
                acc1 = MFMA(ah, bfh[5 + c * 2], acc1);
                acc0 = MFMA(ah, bfl[c * 2 + 0], acc0);
                acc1 = MFMA(ah, bfl[c * 2 + 1], acc1);
            }

            GATES(acc0, acc1, (float)creg[g].x, (float)creg[g].y, cn0, cn1, hn0, hn1);

            const int gy   = y0 + lr;
            const int colm = gx0 + m0;
            const int gxa  = x0 + colm;
            const bool rowok = (lr >= 1) && (lr <= SH) && ((unsigned)gy < HH);
            const bool c0ok = rowok && (colm >= 1) && (colm <= SW) && ((unsigned)gxa < WW);
            const bool c1ok = rowok && (colm + 1 <= SW) && ((unsigned)(gxa + 1) < WW);
            const size_t base = ((size_t)(b * HH + gy) * WW + gxa) * FF + fc;
            if (c0ok) {
                hout[base] = (_Float16)hn0;
                cout[base] = (_Float16)cn0;
            }
            if (c1ok) {
                hout[base + FF] = (_Float16)hn1;
                cout[base + FF] = (_Float16)cn1;
            }
        }
    }
}

// ---------------------------------------------------------------------------
// Last step (t=4) + fused epilogue. Non-overlapping 32x16 tiles (r16 verbatim).
// ---------------------------------------------------------------------------
__global__ __launch_bounds__(256) void lstm_last(
    const float* __restrict__ xg,
    const _Float16* __restrict__ blob,
    const float* __restrict__ bias,
    const _Float16* __restrict__ hin,   // h(3)
    const _Float16* __restrict__ cin,   // c(3) plain
    const float* __restrict__ gamma, const float* __restrict__ beta,
    const float* __restrict__ mean,  const float* __restrict__ var,
    const float* __restrict__ dw,    const float* __restrict__ db,
    float* __restrict__ out)            // [B,H,W,2]
{
    __shared__ half8 hls[LH * LW];
    __shared__ half4 xls[LH * LW];

    const int tid  = threadIdx.x;
    const int lane = tid & 63, wave = tid >> 6;
    const int quad = lane >> 4, nlo = lane & 15;
    const bool lo8 = (nlo < 8);
    const int fc = nlo & 7;
    const int m0 = quad * 4 + (lo8 ? 0 : 2);
    const int bx = blockIdx.x, by = blockIdx.y, b = blockIdx.z;
    const int t = TT - 1;

    half8 bfh[10], bfl[6];
#pragma unroll
    for (int i = 0; i < 10; ++i)
        bfh[i] = *(const half8*)(blob + ((size_t)i * 64 + lane) * 8);
#pragma unroll
    for (int i = 0; i < 6; ++i)
        bfl[i] = *(const half8*)(blob + ((size_t)(10 + i) * 64 + lane) * 8);

    const float bv0 = bias[nlo] * (-LOG2E);
    const float bv1 = bias[16 + nlo] * (lo8 ? 2.0f * LOG2E : -LOG2E);

    float xr[3][3];
    bool  xin[3];
#pragma unroll
    for (int k = 0; k < 3; ++k) {
        const int l = tid + k * 256;
        const bool in = (l < LH * LW);
        xin[k] = in;
        int r = l / LW, c = l - r * LW;
        int gy = by * THT + r - 1, gx = bx * TW + c - 1;
        const bool inb = in && (unsigned)gy < HH && (unsigned)gx < WW;
        const float* p = xg + (((size_t)(b * TT + t) * HH + gy) * WW + gx) * CIN;
        xr[k][0] = inb ? p[0] : 0.0f;
        xr[k][1] = inb ? p[1] : 0.0f;
        xr[k][2] = inb ? p[2] : 0.0f;
    }
    half8 hr[3];
#pragma unroll
    for (int k = 0; k < 3; ++k) {
        const int l = tid + k * 256;
        const bool in = (l < LH * LW);
        int r = l / LW, c = l - r * LW;
        int gy = by * THT + r - 1, gx = bx * TW + c - 1;
        const bool inb = in && (unsigned)gy < HH && (unsigned)gx < WW;
        half8 v = {(_Float16)0, (_Float16)0, (_Float16)0, (_Float16)0,
                   (_Float16)0, (_Float16)0, (_Float16)0, (_Float16)0};
        if (inb) v = *(const half8*)(hin + ((size_t)(b * HH + gy) * WW + gx) * FF);
        hr[k] = v;
    }
    half2t cpre[NG];
#pragma unroll
    for (int g = 0; g < NG; ++g) {
        const int lr  = wave * 4 + (g >> 1);
        const int gx0 = (g & 1) * 16;
        const int gy  = by * THT + lr;
        const int gxa = bx * TW + gx0 + m0;
        const _Float16* cp = cin + ((size_t)(b * HH + gy) * WW + gxa) * FF + fc;
        half2t cv; cv.x = cp[0]; cv.y = cp[FF];
        cpre[g] = cv;
    }

#pragma unroll
    for (int k = 0; k < 3; ++k) {
        if (xin[k]) {
            half4 vh;
            vh.x = (_Float16)xr[k][0];
            vh.y = (_Float16)xr[k][1];
            vh.z = (_Float16)xr[k][2];
            vh.w = (_Float16)0;
            xls[tid + k * 256] = vh;
            hls[tid + k * 256] = hr[k];
        }
    }
    __syncthreads();

    const float bn_s = gamma[fc] * rsqrtf(var[fc] + 1e-3f);
    const float bn_b = beta[fc] - mean[fc] * bn_s;
    const float dw0 = dw[fc * 2 + 0], dw1 = dw[fc * 2 + 1];
    const float db0 = db[0], db1 = db[1];

#pragma unroll
    for (int g = 0; g < NG; ++g) {
        const int lr  = wave * 4 + (g >> 1);
        const int gx0 = (g & 1) * 16;
        const int lc  = gx0 + nlo;

        const int t0 = 2 * quad, t1 = t0 + 1;
        half4 p  = xls[(lr + t0 / 3) * LW + lc + t0 % 3];
        half4 q  = xls[(lr + t1 / 3) * LW + lc + t1 % 3];
        half4 s8 = xls[(lr + 2) * LW + lc + 2];
        half8 a_xA = (half8){p.x, p.y, p.z, p.w, q.x, q.y, q.z, q.w};
        half8 a_xB = (half8){s8.x, s8.y, s8.z, s8.w, s8.x, s8.y, s8.z, s8.w};

        floatx4 acc0 = {bv0, bv0, bv0, bv0};
        floatx4 acc1 = {bv1, bv1, bv1, bv1};
        acc0 = MFMA(a_xA, bfh[0], acc0);  acc1 = MFMA(a_xA, bfh[1], acc1);
        acc0 = MFMA(a_xB, bfh[2], acc0);  acc1 = MFMA(a_xB, bfh[3], acc1);
#pragma unroll
        for (int c = 0; c < 3; ++c) {
            int tap = c * 4 + quad;
            if (tap > 8) tap = 8;
            half8 ah = hls[(lr + tap / 3) * LW + lc + tap % 3];
            acc0 = MFMA(ah, bfh[4 + c * 2], acc0);
            acc1 = MFMA(ah, bfh[5 + c * 2], acc1);
            acc0 = MFMA(ah, bfl[c * 2 + 0], acc0);
            acc1 = MFMA(ah, bfl[c * 2 + 1], acc1);
        }

        GATES(acc0, acc1, (float)cpre[g].x, (float)cpre[g].y, cn0, cn1, hn0, hn1);
        (void)cn0; (void)cn1;

        const int gy = by * THT + lr;
        float y0 = bn_s * hn0 + bn_b; y0 = (y0 >= 0.f) ? y0 : 0.3f * y0;
        float y1 = bn_s * hn1 + bn_b; y1 = (y1 >= 0.f) ? y1 : 0.3f * y1;
        float p00 = y0 * dw0, p01 = y0 * dw1;
        float p10 = y1 * dw0, p11 = y1 * dw1;
#pragma unroll
        for (int m = 1; m <= 4; m <<= 1) {
            p00 += __shfl_xor(p00, m, 64);
            p01 += __shfl_xor(p01, m, 64);
            p10 += __shfl_xor(p10, m, 64);
            p11 += __shfl_xor(p11, m, 64);
        }
        const int j = nlo & 7;
        if (j < 4) {
            const int px = m0 + (j >> 1);
            const int k  = j & 1;
            float val = (j == 0 ? p00 : j == 1 ? p01 : j == 2 ? p10 : p11)
                        + (k ? db1 : db0);
            out[((size_t)(b * HH + gy) * WW + bx * TW + gx0 + px) * 2 + k] = val;
        }
    }
}

extern "C" void kernel_launch(void* const* d_in, const int* in_sizes, int n_in,
                              void* d_out, int out_size, void* d_ws, size_t ws_size,
                              hipStream_t stream) {
    const float* x     = (const float*)d_in[0];
    const float* wk    = (const float*)d_in[1];
    const float* wr    = (const float*)d_in[2];
    const float* bias  = (const float*)d_in[3];
    const float* gamma = (const float*)d_in[4];
    const float* beta  = (const float*)d_in[5];
    const float* mean  = (const float*)d_in[6];
    const float* var   = (const float*)d_in[7];
    const float* dw    = (const float*)d_in[8];
    const float* db    = (const float*)d_in[9];
    float* out = (float*)d_out;

    // ws: blob 32KB | hA | hB | cA | cB (each 16.78MB fp16) = 67.2MB total
    const size_t state = (size_t)BB * HH * WW * FF;
    _Float16* blob = (_Float16*)d_ws;
    _Float16* hA = (_Float16*)((char*)d_ws + 32768);
    _Float16* hB = hA + state;
    _Float16* cA = hB + state;
    _Float16* cB = cA + state;

    build_frags<<<1, 64, 0, stream>>>(wk, wr, blob);

    dim3 block(256);
    // pair (0,1): no h/c input; writes h(1)->hA, c(1)->cA
    lstm_pair<1><<<dim3(NBLKP), block, 0, stream>>>(x, 0, blob, bias,
                                                    nullptr, hA, nullptr, cA);
    // pair (2,3): reads hA/cA; writes h(3)->hB, c(3)->cB
    lstm_pair<0><<<dim3(NBLKP), block, 0, stream>>>(x, 2, blob, bias,
                                                    hA, hB, cA, cB);
    // step 4 + epilogue
    dim3 lgrid(WW / TW, HH / THT, BB);
    lstm_last<<<lgrid, block, 0, stream>>>(x, blob, bias, hB, cB,
                                           gamma, beta, mean, var, dw, db, out);
}